// Round 1
// baseline (304.405 us; speedup 1.0000x reference)
//
#include <hip/hip_runtime.h>

// Problem constants (from reference):
//   pred_heatmap: (B=16, L=68, H=224, W=224) fp32
//   true_landmarks: (16, 68, 2) fp32
//   bell: (128, 128) fp32
//   out: scalar fp32 = mean((pred - true_heatmap)^2)
#define N_IMG   1088        // B*L
#define IMG_HW  50176       // 224*224
#define W_DIM   224
#define H_DIM   224
#define ROW_F4  56          // 224/4
#define IMG_F4  12544       // 224*56
#define DELTA_  128
#define HALF_   64
#define N_TOT   54591488.0  // 1088*50176

// Phase 1: one block per (b,l) image; partial sum of squared diff -> ws[img]
__global__ __launch_bounds__(256) void lm_loss_partial(
        const float* __restrict__ pred,
        const float* __restrict__ lms,
        const float* __restrict__ bell,
        float* __restrict__ partials) {
    const int img = blockIdx.x;
    const float4* __restrict__ p4 =
        (const float4*)(pred + (size_t)img * IMG_HW);

    // landmark for this image (broadcast via scalar cache)
    const float ly = lms[img * 2 + 0];
    const float lx = lms[img * 2 + 1];
    const int y_r = (int)rintf(ly);   // round half-to-even, matches jnp.round
    const int x_r = (int)rintf(lx);

    float acc = 0.0f;
    for (int f = threadIdx.x; f < IMG_F4; f += 256) {
        const int h  = f / ROW_F4;              // magic-mul, cheap
        const int w  = (f - h * ROW_F4) * 4;
        const float4 p = p4[f];

        float t0 = 0.f, t1 = 0.f, t2 = 0.f, t3 = 0.f;
        const int bx = h - x_r + HALF_;         // window row index (H axis)
        if ((unsigned)bx < (unsigned)DELTA_) {
            const float* __restrict__ row = bell + bx * DELTA_;
            const int by = w - y_r + HALF_;     // window col index (W axis)
            if ((unsigned)(by + 0) < (unsigned)DELTA_) t0 = row[by + 0];
            if ((unsigned)(by + 1) < (unsigned)DELTA_) t1 = row[by + 1];
            if ((unsigned)(by + 2) < (unsigned)DELTA_) t2 = row[by + 2];
            if ((unsigned)(by + 3) < (unsigned)DELTA_) t3 = row[by + 3];
        }
        const float d0 = p.x - t0;
        const float d1 = p.y - t1;
        const float d2 = p.z - t2;
        const float d3 = p.w - t3;
        acc += d0 * d0;
        acc += d1 * d1;
        acc += d2 * d2;
        acc += d3 * d3;
    }

    // wave-64 shuffle reduction
    #pragma unroll
    for (int off = 32; off > 0; off >>= 1)
        acc += __shfl_down(acc, off, 64);

    __shared__ float wsum[4];                   // 256 threads = 4 waves
    const int lane = threadIdx.x & 63;
    const int wid  = threadIdx.x >> 6;
    if (lane == 0) wsum[wid] = acc;
    __syncthreads();
    if (threadIdx.x == 0)
        partials[img] = wsum[0] + wsum[1] + wsum[2] + wsum[3];
}

// Phase 2: single block reduces the 1088 partials, writes mean
__global__ __launch_bounds__(256) void lm_loss_final(
        const float* __restrict__ partials,
        float* __restrict__ out) {
    double acc = 0.0;
    for (int i = threadIdx.x; i < N_IMG; i += 256)
        acc += (double)partials[i];

    #pragma unroll
    for (int off = 32; off > 0; off >>= 1)
        acc += __shfl_down(acc, off, 64);

    __shared__ double wsum[4];
    const int lane = threadIdx.x & 63;
    const int wid  = threadIdx.x >> 6;
    if (lane == 0) wsum[wid] = acc;
    __syncthreads();
    if (threadIdx.x == 0) {
        const double total = wsum[0] + wsum[1] + wsum[2] + wsum[3];
        out[0] = (float)(total / N_TOT);
    }
}

extern "C" void kernel_launch(void* const* d_in, const int* in_sizes, int n_in,
                              void* d_out, int out_size, void* d_ws, size_t ws_size,
                              hipStream_t stream) {
    const float* pred = (const float*)d_in[0];   // (16,68,224,224)
    const float* lms  = (const float*)d_in[1];   // (16,68,2)
    const float* bell = (const float*)d_in[2];   // (128,128)
    float* out        = (float*)d_out;           // scalar
    float* partials   = (float*)d_ws;            // 1088 floats (ws re-poisoned
                                                 // each call; fully rewritten)

    lm_loss_partial<<<N_IMG, 256, 0, stream>>>(pred, lms, bell, partials);
    lm_loss_final<<<1, 256, 0, stream>>>(partials, out);
}